// Round 4
// baseline (2444.928 us; speedup 1.0000x reference)
//
#include <hip/hip_runtime.h>
#include <cstdint>
#include <cstddef>

// APPNP: h0 = relu(x@W1+b1)@W2+b2 ; 10x { h = 0.9*A_hat h + 0.1*h0 } ; log_softmax
// N=100000, E=3200000, F=512, H=256, C=64
// R4: XCD-range-partitioned count/fill (kills 16x write amplification seen in R3:
//     WRITE_SIZE=195MB for a 12.8MB array); feature-split prop (64B gather rows,
//     working set 6.4MB/half -> ~2x L2 hit rate; 4 edges per VMEM instr).
// ws budget ~53 MB.

typedef _Float16 half8 __attribute__((ext_vector_type(8)));
typedef float floatx4 __attribute__((ext_vector_type(4)));

__device__ inline float2 unpack2(uint u) {
    union { uint u; _Float16 h[2]; } c; c.u = u;
    return make_float2((float)c.h[0], (float)c.h[1]);
}
__device__ inline uint pack2(float a, float b) {
    union { uint u; _Float16 h[2]; } c; c.h[0] = (_Float16)a; c.h[1] = (_Float16)b;
    return c.u;
}

// ---------------- weight pre-transpose (fp32 -> f16, [k][c] -> [c][k]) ----------------
__global__ void transpose_w1(const float* __restrict__ W1, _Float16* __restrict__ W1t) {
    int i = blockIdx.x * 256 + threadIdx.x;          // over 512*256
    if (i < 512 * 256) {
        int k = i >> 8, c = i & 255;
        W1t[(size_t)c * 512 + k] = (_Float16)W1[i];
    }
}
__global__ void transpose_w2(const float* __restrict__ W2, _Float16* __restrict__ W2t) {
    int i = blockIdx.x * 256 + threadIdx.x;          // over 256*64
    if (i < 256 * 64) {
        int k = i >> 6, c = i & 63;
        W2t[(size_t)c * 256 + k] = (_Float16)W2[i];
    }
}

// ---------------- fused 2-layer MLP via f16 MFMA ----------------
// block = 256 thr = 4 waves; BM=32 rows/block (n=100000 -> 3125 blocks exactly).
// Output layout: SPLIT h0s[half][node][32] f16 (64B rows for prop).
__global__ __launch_bounds__(256) void mlp_kernel(
    const float* __restrict__ x, const _Float16* __restrict__ W1t,
    const float* __restrict__ b1, const _Float16* __restrict__ W2t,
    const float* __restrict__ b2, _Float16* __restrict__ h0s, int n)
{
    __shared__ __align__(16) _Float16 xs[32][520];        // 33.3 KB
    __shared__ __align__(16) _Float16 w1ts_raw[256 * 40]; // 20.5 KB; also hmid[32][264]
    _Float16 (*w1ts)[40]  = (_Float16(*)[40])w1ts_raw;
    _Float16 (*hmid)[264] = (_Float16(*)[264])w1ts_raw;

    const int tid  = threadIdx.x;
    const int lane = tid & 63;
    const int wid  = tid >> 6;
    const int r0blk = blockIdx.x * 32;
    const int lr = lane & 15;      // frag row/col index
    const int lg = lane >> 4;      // frag k-group

    // ---- load x tile 32x512 fp32 -> f16 LDS ----
    for (int fi = tid; fi < 32 * 128; fi += 256) {
        int r = fi >> 7, k4 = (fi & 127) * 4;
        float4 v = *(const float4*)(x + (size_t)(r0blk + r) * 512 + k4);
        union { short4 s; _Float16 h[4]; } c;
        c.h[0] = (_Float16)v.x; c.h[1] = (_Float16)v.y;
        c.h[2] = (_Float16)v.z; c.h[3] = (_Float16)v.w;
        *(short4*)&xs[r][k4] = c.s;
    }

    // ---- phase 1: hmid = relu(x @ W1 + b1), 32 x 256 ----
    const int wr = wid >> 1, wc = wid & 1;
    floatx4 acc1[8];
#pragma unroll
    for (int ct = 0; ct < 8; ++ct) {
        float b = b1[wc * 128 + ct * 16 + lr];
        acc1[ct] = (floatx4){b, b, b, b};
    }

    for (int kk = 0; kk < 512; kk += 32) {
        __syncthreads();
        for (int fi = tid; fi < 1024; fi += 256) {
            int c = fi >> 2, seg = (fi & 3) * 8;
            *(int4*)&w1ts[c][seg] = *(const int4*)&W1t[(size_t)c * 512 + kk + seg];
        }
        __syncthreads();
        half8 a = *(const half8*)&xs[wr * 16 + lr][kk + lg * 8];
#pragma unroll
        for (int ct = 0; ct < 8; ++ct) {
            half8 b = *(const half8*)&w1ts[wc * 128 + ct * 16 + lr][lg * 8];
            acc1[ct] = __builtin_amdgcn_mfma_f32_16x16x32_f16(a, b, acc1[ct], 0, 0, 0);
        }
    }

    __syncthreads();
#pragma unroll
    for (int ct = 0; ct < 8; ++ct) {
#pragma unroll
        for (int r = 0; r < 4; ++r) {
            float v = fmaxf(acc1[ct][r], 0.f);
            hmid[wr * 16 + lg * 4 + r][wc * 128 + ct * 16 + lr] = (_Float16)v;
        }
    }
    __syncthreads();

    // ---- phase 2: h0 = hmid @ W2 + b2, 32 x 64, write split layout ----
    const int rt = wid >> 1, ct2 = (wid & 1) * 2;
    floatx4 acc2[2] = {(floatx4){0,0,0,0}, (floatx4){0,0,0,0}};
    for (int kk = 0; kk < 256; kk += 32) {
        half8 a = *(const half8*)&hmid[rt * 16 + lr][kk + lg * 8];
#pragma unroll
        for (int q = 0; q < 2; ++q) {
            half8 b = *(const half8*)&W2t[(size_t)((ct2 + q) * 16 + lr) * 256 + kk + lg * 8];
            acc2[q] = __builtin_amdgcn_mfma_f32_16x16x32_f16(a, b, acc2[q], 0, 0, 0);
        }
    }
#pragma unroll
    for (int q = 0; q < 2; ++q) {
        int col = (ct2 + q) * 16 + lr;
        int half_ = col >> 5, cc = col & 31;
        float bb = b2[col];
#pragma unroll
        for (int r = 0; r < 4; ++r) {
            int row = r0blk + rt * 16 + lg * 4 + r;
            h0s[((size_t)half_ * n + row) * 32 + cc] = (_Float16)(acc2[q][r] + bb);
        }
    }
}

// ---------------- graph preprocessing (CSR by dst, XCD-range partitioned) ----------------
__global__ void init_counts_kernel(int* __restrict__ counts, int n) {
    int i = blockIdx.x * blockDim.x + threadIdx.x;
    if (i < n) counts[i] = 1;   // self-loop
}

// blocks with blockIdx.x&7 == r handle dst range [r*rs, min((r+1)*rs, n)).
// Each range-group streams the FULL dst list (L3-resident after first group).
__global__ void count_kernel(const int* __restrict__ dstL, int* __restrict__ counts,
                             int e, int rs, int n) {
    const int r = blockIdx.x & 7;
    const int g = blockIdx.x >> 3;
    const int B = gridDim.x >> 3;
    const int lo = r * rs;
    const int hi = min(lo + rs, n);
    for (int i = g * blockDim.x + threadIdx.x; i < e; i += B * blockDim.x) {
        int d = dstL[i];
        if (d >= lo && d < hi) atomicAdd(&counts[d], 1);
    }
}

__global__ void dinv_kernel(const int* __restrict__ counts, float* __restrict__ dinv, int n) {
    int i = blockIdx.x * blockDim.x + threadIdx.x;
    if (i < n) dinv[i] = 1.0f / sqrtf((float)counts[i]);   // deg >= 1 (self-loop)
}

__global__ __launch_bounds__(256) void scan_a(const int* __restrict__ counts,
                                              int* __restrict__ rowptr,
                                              int* __restrict__ bsums, int n)
{
    __shared__ int s[256];
    const int t = threadIdx.x;
    const int i = blockIdx.x * 256 + t;
    int v = (i < n) ? (counts[i] - 1) : 0;
    s[t] = v;
    __syncthreads();
    for (int off = 1; off < 256; off <<= 1) {
        int add = (t >= off) ? s[t - off] : 0;
        __syncthreads();
        s[t] += add;
        __syncthreads();
    }
    if (i < n) rowptr[i] = s[t] - v;
    if (t == 255) bsums[blockIdx.x] = s[255];
}

__global__ __launch_bounds__(512) void scan_b(const int* __restrict__ bsums,
                                              int* __restrict__ boff, int nb)
{
    __shared__ int s[512];
    const int t = threadIdx.x;
    int v = (t < nb) ? bsums[t] : 0;
    s[t] = v;
    __syncthreads();
    for (int off = 1; off < 512; off <<= 1) {
        int add = (t >= off) ? s[t - off] : 0;
        __syncthreads();
        s[t] += add;
        __syncthreads();
    }
    if (t < nb) boff[t] = s[t] - v;
}

__global__ __launch_bounds__(256) void scan_c(int* __restrict__ rowptr,
                                              int* __restrict__ cursor,
                                              const int* __restrict__ boff, int n, int e)
{
    int i = blockIdx.x * 256 + threadIdx.x;
    if (i < n) {
        int v = rowptr[i] + boff[blockIdx.x];
        rowptr[i] = v;
        cursor[i] = v;
    }
    if (i == 0) rowptr[n] = e;
}

// range-partitioned fill: XCD r writes only its contiguous CSR segment.
__global__ void fill_kernel(const int* __restrict__ srcL, const int* __restrict__ dstL,
                            int* __restrict__ cursor, int* __restrict__ srcs,
                            int e, int rs, int n) {
    const int r = blockIdx.x & 7;
    const int g = blockIdx.x >> 3;
    const int B = gridDim.x >> 3;
    const int lo = r * rs;
    const int hi = min(lo + rs, n);
    for (int i = g * blockDim.x + threadIdx.x; i < e; i += B * blockDim.x) {
        int d = dstL[i];
        if (d >= lo && d < hi) {
            int pos = atomicAdd(&cursor[d], 1);
            srcs[pos] = srcL[i];
        }
    }
}

// ---------------- APPNP propagation step (split f16 storage) ----------------
// h layout: hu[half][node][16 uints] (64B rows). grid.y = half.
// wave per (node,half): g=lane>>4 edge slot (4 edges/instr), u=lane&15 uint idx.
__global__ __launch_bounds__(256) void prop_kernel(
    const uint* __restrict__ hu, const uint* __restrict__ h0u,
    uint* __restrict__ hnu, const int* __restrict__ rowptr,
    const int* __restrict__ srcs, const float* __restrict__ dinv, int n)
{
    const int node = (blockIdx.x * blockDim.x + threadIdx.x) >> 6;
    if (node >= n) return;
    const int lane = threadIdx.x & 63;
    const int g = lane >> 4, u = lane & 15;
    const size_t hb = (size_t)blockIdx.y * n;
    const int e0 = rowptr[node], e1 = rowptr[node + 1];
    float accx = 0.f, accy = 0.f;
    for (int e = e0 + g; e < e1; e += 4) {
        int s = srcs[e];
        float w = dinv[s];
        float2 f = unpack2(hu[(hb + s) * 16 + u]);
        accx += w * f.x; accy += w * f.y;
    }
    accx += __shfl_xor(accx, 16); accy += __shfl_xor(accy, 16);
    accx += __shfl_xor(accx, 32); accy += __shfl_xor(accy, 32);

    const float di = dinv[node];
    float2 self = unpack2(hu[(hb + node) * 16 + u]);
    float2 anc  = unpack2(h0u[(hb + node) * 16 + u]);
    float ox = 0.9f * (di * accx + self.x * di * di) + 0.1f * anc.x;
    float oy = 0.9f * (di * accy + self.y * di * di) + 0.1f * anc.y;
    if (g == 0) hnu[(hb + node) * 16 + u] = pack2(ox, oy);
}

// ---------------- log_softmax over C=64 (split f16 in, fp32 out) ----------------
__global__ __launch_bounds__(256) void logsoftmax_kernel(
    const _Float16* __restrict__ h, float* __restrict__ out, int n)
{
    const int row = (blockIdx.x * blockDim.x + threadIdx.x) >> 6;
    const int lane = threadIdx.x & 63;
    if (row >= n) return;
    float v = (float)h[((size_t)(lane >> 5) * n + row) * 32 + (lane & 31)];
    float m = v;
#pragma unroll
    for (int o = 32; o > 0; o >>= 1) m = fmaxf(m, __shfl_xor(m, o));
    float ex = expf(v - m);
    float s = ex;
#pragma unroll
    for (int o = 32; o > 0; o >>= 1) s += __shfl_xor(s, o);
    out[(size_t)row * 64 + lane] = v - m - logf(s);
}

// ---------------- launcher ----------------
extern "C" void kernel_launch(void* const* d_in, const int* in_sizes, int n_in,
                              void* d_out, int out_size, void* d_ws, size_t ws_size,
                              hipStream_t stream)
{
    const float* x  = (const float*)d_in[0];
    const int*   ei = (const int*)d_in[1];
    const float* W1 = (const float*)d_in[2];
    const float* b1 = (const float*)d_in[3];
    const float* W2 = (const float*)d_in[4];
    const float* b2 = (const float*)d_in[5];
    float* out = (float*)d_out;

    const int n = in_sizes[0] / 512;    // 100000
    const int e = in_sizes[1] / 2;      // 3200000
    const int* srcL = ei;
    const int* dstL = ei + e;

    char* wsb = (char*)d_ws;
    size_t off = 0;
    auto alloc = [&](size_t bytes) -> void* {
        void* p = wsb + off;
        off = (off + bytes + 255) & ~(size_t)255;
        return p;
    };
    // ~53 MB total
    _Float16* h0s = (_Float16*)alloc((size_t)n * 64 * 2);  // 12.8 MB (split layout)
    _Float16* hp0 = (_Float16*)alloc((size_t)n * 64 * 2);  // 12.8 MB
    _Float16* hp1 = (_Float16*)alloc((size_t)n * 64 * 2);  // 12.8 MB
    int*   srcs   = (int*)alloc((size_t)e * 4);            // 12.8 MB
    float* dinv   = (float*)alloc((size_t)n * 4);
    int*   counts = (int*)alloc((size_t)n * 4);            // reused as cursor
    int*   rowptr = (int*)alloc((size_t)(n + 1) * 4);
    int*   bsums  = (int*)alloc(4096);
    int*   boff   = (int*)alloc(4096);
    _Float16* W1t = (_Float16*)alloc((size_t)512 * 256 * 2);
    _Float16* W2t = (_Float16*)alloc((size_t)256 * 64 * 2);
    int* cursor = counts;

    const int nb = (n + 255) / 256;     // 391 (< 512 for scan_b)
    const int rs = (n + 7) / 8;         // 12500 per XCD range

    transpose_w1<<<(512 * 256 + 255) / 256, 256, 0, stream>>>(W1, W1t);
    transpose_w2<<<(256 * 64 + 255) / 256, 256, 0, stream>>>(W2, W2t);

    mlp_kernel<<<n / 32, 256, 0, stream>>>(x, W1t, b1, W2t, b2, h0s, n);

    init_counts_kernel<<<nb, 256, 0, stream>>>(counts, n);
    count_kernel<<<1024, 256, 0, stream>>>(dstL, counts, e, rs, n);
    dinv_kernel<<<nb, 256, 0, stream>>>(counts, dinv, n);
    scan_a<<<nb, 256, 0, stream>>>(counts, rowptr, bsums, n);
    scan_b<<<1, 512, 0, stream>>>(bsums, boff, nb);
    scan_c<<<nb, 256, 0, stream>>>(rowptr, cursor, boff, n, e);
    fill_kernel<<<1024, 256, 0, stream>>>(srcL, dstL, cursor, srcs, e, rs, n);

    // ping-pong: h0s -> hp0 -> hp1 -> ... iter9 (odd) lands in hp1
    const int pgrid = (n * 64 + 255) / 256;
    dim3 pg(pgrid, 2);
    const uint* hin = (const uint*)h0s;
    uint* bufs[2] = {(uint*)hp0, (uint*)hp1};
    for (int it = 0; it < 10; ++it) {
        uint* hn = bufs[it & 1];
        prop_kernel<<<pg, 256, 0, stream>>>(hin, (const uint*)h0s, hn,
                                            rowptr, srcs, dinv, n);
        hin = hn;
    }
    logsoftmax_kernel<<<pgrid, 256, 0, stream>>>((const _Float16*)hin, out, n);
}

// Round 5
// 1587.542 us; speedup vs baseline: 1.5401x; 1.5401x over previous
//
#include <hip/hip_runtime.h>
#include <cstdint>
#include <cstddef>

// APPNP: h0 = relu(x@W1+b1)@W2+b2 ; 10x { h = 0.9*A_hat h + 0.1*h0 } ; log_softmax
// N=100000, E=3200000, F=512, H=256, C=64
// R5: revert prop to unified 128B rows (R4 split halved fetch-granule utilization
//     and doubled index traffic); prop 8-deep gather pipeline. MLP: no W-staging
//     (W1t 256KB is L2-hot; read B-frags direct from global) -> 2 barriers total,
//     no staging bank conflicts, 50KB LDS -> 3 blocks/CU.
// ws budget ~53 MB (R1 failed ~104 MB).

typedef _Float16 half8 __attribute__((ext_vector_type(8)));
typedef float floatx4 __attribute__((ext_vector_type(4)));

__device__ inline float2 unpack2(uint u) {
    union { uint u; _Float16 h[2]; } c; c.u = u;
    return make_float2((float)c.h[0], (float)c.h[1]);
}
__device__ inline uint pack2(float a, float b) {
    union { uint u; _Float16 h[2]; } c; c.h[0] = (_Float16)a; c.h[1] = (_Float16)b;
    return c.u;
}

// ---------------- weight pre-transpose (fp32 -> f16, [k][c] -> [c][k]) ----------------
__global__ void transpose_w1(const float* __restrict__ W1, _Float16* __restrict__ W1t) {
    int i = blockIdx.x * 256 + threadIdx.x;          // over 512*256
    if (i < 512 * 256) {
        int k = i >> 8, c = i & 255;
        W1t[(size_t)c * 512 + k] = (_Float16)W1[i];
    }
}
__global__ void transpose_w2(const float* __restrict__ W2, _Float16* __restrict__ W2t) {
    int i = blockIdx.x * 256 + threadIdx.x;          // over 256*64
    if (i < 256 * 64) {
        int k = i >> 6, c = i & 63;
        W2t[(size_t)c * 256 + k] = (_Float16)W2[i];
    }
}

// ---------------- fused 2-layer MLP via f16 MFMA, B-frags from L2 ----------------
// block = 256 thr = 4 waves; BM=32 rows/block (3125 blocks).
// frag maps (16x16x32): A[row=l&15][k=(l>>4)*8+j]; B[k=(l>>4)*8+j][col=l&15];
//                       D[row=(l>>4)*4+r][col=l&15]   (m89-verified)
__global__ __launch_bounds__(256) void mlp_kernel(
    const float* __restrict__ x, const _Float16* __restrict__ W1t,
    const float* __restrict__ b1, const _Float16* __restrict__ W2t,
    const float* __restrict__ b2, _Float16* __restrict__ h0h, int n)
{
    __shared__ __align__(16) _Float16 xs[32][520];    // 33.3 KB
    __shared__ __align__(16) _Float16 hmid[32][264];  // 16.9 KB  (total 50.2 KB)

    const int tid  = threadIdx.x;
    const int lane = tid & 63;
    const int wid  = tid >> 6;
    const int r0blk = blockIdx.x * 32;
    const int lr = lane & 15;      // frag row/col index
    const int lg = lane >> 4;      // frag k-group

    // ---- load x tile 32x512 fp32 -> f16 LDS ----
    for (int fi = tid; fi < 32 * 128; fi += 256) {
        int r = fi >> 7, k4 = (fi & 127) * 4;
        float4 v = *(const float4*)(x + (size_t)(r0blk + r) * 512 + k4);
        union { short4 s; _Float16 h[4]; } c;
        c.h[0] = (_Float16)v.x; c.h[1] = (_Float16)v.y;
        c.h[2] = (_Float16)v.z; c.h[3] = (_Float16)v.w;
        *(short4*)&xs[r][k4] = c.s;
    }
    __syncthreads();

    // ---- phase 1: hmid = relu(x @ W1 + b1), 32 x 256; B direct from global ----
    const int wr = wid >> 1, wc = wid & 1;
    floatx4 acc1[8];
#pragma unroll
    for (int ct = 0; ct < 8; ++ct) {
        float b = b1[wc * 128 + ct * 16 + lr];
        acc1[ct] = (floatx4){b, b, b, b};
    }

#pragma unroll 2
    for (int kk = 0; kk < 512; kk += 32) {
        half8 a = *(const half8*)&xs[wr * 16 + lr][kk + lg * 8];
        half8 bfr[8];
#pragma unroll
        for (int ct = 0; ct < 8; ++ct)
            bfr[ct] = *(const half8*)&W1t[(size_t)(wc * 128 + ct * 16 + lr) * 512 + kk + lg * 8];
#pragma unroll
        for (int ct = 0; ct < 8; ++ct)
            acc1[ct] = __builtin_amdgcn_mfma_f32_16x16x32_f16(a, bfr[ct], acc1[ct], 0, 0, 0);
    }

#pragma unroll
    for (int ct = 0; ct < 8; ++ct) {
#pragma unroll
        for (int r = 0; r < 4; ++r) {
            float v = fmaxf(acc1[ct][r], 0.f);
            hmid[wr * 16 + lg * 4 + r][wc * 128 + ct * 16 + lr] = (_Float16)v;
        }
    }
    __syncthreads();

    // ---- phase 2: h0 = hmid @ W2 + b2, 32 x 64, unified layout ----
    const int rt = wid >> 1, ct2 = (wid & 1) * 2;
    floatx4 acc2[2] = {(floatx4){0,0,0,0}, (floatx4){0,0,0,0}};
#pragma unroll 2
    for (int kk = 0; kk < 256; kk += 32) {
        half8 a = *(const half8*)&hmid[rt * 16 + lr][kk + lg * 8];
#pragma unroll
        for (int q = 0; q < 2; ++q) {
            half8 b = *(const half8*)&W2t[(size_t)((ct2 + q) * 16 + lr) * 256 + kk + lg * 8];
            acc2[q] = __builtin_amdgcn_mfma_f32_16x16x32_f16(a, b, acc2[q], 0, 0, 0);
        }
    }
#pragma unroll
    for (int q = 0; q < 2; ++q) {
        int col = (ct2 + q) * 16 + lr;
        float bb = b2[col];
#pragma unroll
        for (int r = 0; r < 4; ++r) {
            int row = r0blk + rt * 16 + lg * 4 + r;
            h0h[(size_t)row * 64 + col] = (_Float16)(acc2[q][r] + bb);
        }
    }
}

// ---------------- graph preprocessing (CSR by dst, XCD-range partitioned) ----------------
__global__ void init_counts_kernel(int* __restrict__ counts, int n) {
    int i = blockIdx.x * blockDim.x + threadIdx.x;
    if (i < n) counts[i] = 1;   // self-loop
}

__global__ void count_kernel(const int* __restrict__ dstL, int* __restrict__ counts,
                             int e, int rs, int n) {
    const int r = blockIdx.x & 7;
    const int g = blockIdx.x >> 3;
    const int B = gridDim.x >> 3;
    const int lo = r * rs;
    const int hi = min(lo + rs, n);
    for (int i = g * blockDim.x + threadIdx.x; i < e; i += B * blockDim.x) {
        int d = dstL[i];
        if (d >= lo && d < hi) atomicAdd(&counts[d], 1);
    }
}

__global__ void dinv_kernel(const int* __restrict__ counts, float* __restrict__ dinv, int n) {
    int i = blockIdx.x * blockDim.x + threadIdx.x;
    if (i < n) dinv[i] = 1.0f / sqrtf((float)counts[i]);   // deg >= 1 (self-loop)
}

__global__ __launch_bounds__(256) void scan_a(const int* __restrict__ counts,
                                              int* __restrict__ rowptr,
                                              int* __restrict__ bsums, int n)
{
    __shared__ int s[256];
    const int t = threadIdx.x;
    const int i = blockIdx.x * 256 + t;
    int v = (i < n) ? (counts[i] - 1) : 0;
    s[t] = v;
    __syncthreads();
    for (int off = 1; off < 256; off <<= 1) {
        int add = (t >= off) ? s[t - off] : 0;
        __syncthreads();
        s[t] += add;
        __syncthreads();
    }
    if (i < n) rowptr[i] = s[t] - v;
    if (t == 255) bsums[blockIdx.x] = s[255];
}

__global__ __launch_bounds__(512) void scan_b(const int* __restrict__ bsums,
                                              int* __restrict__ boff, int nb)
{
    __shared__ int s[512];
    const int t = threadIdx.x;
    int v = (t < nb) ? bsums[t] : 0;
    s[t] = v;
    __syncthreads();
    for (int off = 1; off < 512; off <<= 1) {
        int add = (t >= off) ? s[t - off] : 0;
        __syncthreads();
        s[t] += add;
        __syncthreads();
    }
    if (t < nb) boff[t] = s[t] - v;
}

__global__ __launch_bounds__(256) void scan_c(int* __restrict__ rowptr,
                                              int* __restrict__ cursor,
                                              const int* __restrict__ boff, int n, int e)
{
    int i = blockIdx.x * 256 + threadIdx.x;
    if (i < n) {
        int v = rowptr[i] + boff[blockIdx.x];
        rowptr[i] = v;
        cursor[i] = v;
    }
    if (i == 0) rowptr[n] = e;
}

__global__ void fill_kernel(const int* __restrict__ srcL, const int* __restrict__ dstL,
                            int* __restrict__ cursor, int* __restrict__ srcs,
                            int e, int rs, int n) {
    const int r = blockIdx.x & 7;
    const int g = blockIdx.x >> 3;
    const int B = gridDim.x >> 3;
    const int lo = r * rs;
    const int hi = min(lo + rs, n);
    for (int i = g * blockDim.x + threadIdx.x; i < e; i += B * blockDim.x) {
        int d = dstL[i];
        if (d >= lo && d < hi) {
            int pos = atomicAdd(&cursor[d], 1);
            srcs[pos] = srcL[i];
        }
    }
}

// ---------------- APPNP propagation step (unified f16, 128B rows) ----------------
// one wave per node; half = lane>>5 takes alternate edges (full 128B row per half:
// 32 lanes x 1 packed uint = 64 f16). 4-deep unroll per half -> 8 gathers in flight.
__global__ __launch_bounds__(256) void prop_kernel(
    const uint* __restrict__ hu, const uint* __restrict__ h0u,
    uint* __restrict__ hnu, const int* __restrict__ rowptr,
    const int* __restrict__ srcs, const float* __restrict__ dinv, int n)
{
    const int node = (blockIdx.x * blockDim.x + threadIdx.x) >> 6;
    if (node >= n) return;
    const int lane = threadIdx.x & 63;
    const int half_ = lane >> 5;
    const int p = lane & 31;
    const int e0 = rowptr[node], e1 = rowptr[node + 1];
    float accx = 0.f, accy = 0.f;
    int e = e0 + half_;
    for (; e + 6 < e1; e += 8) {
        int s0 = srcs[e], s1 = srcs[e + 2], s2 = srcs[e + 4], s3 = srcs[e + 6];
        float w0 = dinv[s0], w1 = dinv[s1], w2 = dinv[s2], w3 = dinv[s3];
        float2 f0 = unpack2(hu[(size_t)s0 * 32 + p]);
        float2 f1 = unpack2(hu[(size_t)s1 * 32 + p]);
        float2 f2 = unpack2(hu[(size_t)s2 * 32 + p]);
        float2 f3 = unpack2(hu[(size_t)s3 * 32 + p]);
        accx += w0 * f0.x; accy += w0 * f0.y;
        accx += w1 * f1.x; accy += w1 * f1.y;
        accx += w2 * f2.x; accy += w2 * f2.y;
        accx += w3 * f3.x; accy += w3 * f3.y;
    }
    for (; e < e1; e += 2) {
        int s = srcs[e];
        float w = dinv[s];
        float2 f = unpack2(hu[(size_t)s * 32 + p]);
        accx += w * f.x; accy += w * f.y;
    }
    accx += __shfl_xor(accx, 32);
    accy += __shfl_xor(accy, 32);

    const float di = dinv[node];
    float2 self = unpack2(hu[(size_t)node * 32 + p]);
    float2 anc  = unpack2(h0u[(size_t)node * 32 + p]);
    float ox = 0.9f * (di * accx + self.x * di * di) + 0.1f * anc.x;
    float oy = 0.9f * (di * accy + self.y * di * di) + 0.1f * anc.y;
    if (half_ == 0) hnu[(size_t)node * 32 + p] = pack2(ox, oy);
}

// ---------------- log_softmax over C=64 (f16 in, fp32 out) ----------------
__global__ __launch_bounds__(256) void logsoftmax_kernel(
    const _Float16* __restrict__ h, float* __restrict__ out, int n)
{
    const int row = (blockIdx.x * blockDim.x + threadIdx.x) >> 6;
    const int lane = threadIdx.x & 63;
    if (row >= n) return;
    float v = (float)h[(size_t)row * 64 + lane];
    float m = v;
#pragma unroll
    for (int o = 32; o > 0; o >>= 1) m = fmaxf(m, __shfl_xor(m, o));
    float ex = expf(v - m);
    float s = ex;
#pragma unroll
    for (int o = 32; o > 0; o >>= 1) s += __shfl_xor(s, o);
    out[(size_t)row * 64 + lane] = v - m - logf(s);
}

// ---------------- launcher ----------------
extern "C" void kernel_launch(void* const* d_in, const int* in_sizes, int n_in,
                              void* d_out, int out_size, void* d_ws, size_t ws_size,
                              hipStream_t stream)
{
    const float* x  = (const float*)d_in[0];
    const int*   ei = (const int*)d_in[1];
    const float* W1 = (const float*)d_in[2];
    const float* b1 = (const float*)d_in[3];
    const float* W2 = (const float*)d_in[4];
    const float* b2 = (const float*)d_in[5];
    float* out = (float*)d_out;

    const int n = in_sizes[0] / 512;    // 100000
    const int e = in_sizes[1] / 2;      // 3200000
    const int* srcL = ei;
    const int* dstL = ei + e;

    char* wsb = (char*)d_ws;
    size_t off = 0;
    auto alloc = [&](size_t bytes) -> void* {
        void* p = wsb + off;
        off = (off + bytes + 255) & ~(size_t)255;
        return p;
    };
    // ~53 MB total
    _Float16* h0h = (_Float16*)alloc((size_t)n * 64 * 2);  // 12.8 MB
    _Float16* hp0 = (_Float16*)alloc((size_t)n * 64 * 2);  // 12.8 MB
    _Float16* hp1 = (_Float16*)alloc((size_t)n * 64 * 2);  // 12.8 MB
    int*   srcs   = (int*)alloc((size_t)e * 4);            // 12.8 MB
    float* dinv   = (float*)alloc((size_t)n * 4);
    int*   counts = (int*)alloc((size_t)n * 4);            // reused as cursor
    int*   rowptr = (int*)alloc((size_t)(n + 1) * 4);
    int*   bsums  = (int*)alloc(4096);
    int*   boff   = (int*)alloc(4096);
    _Float16* W1t = (_Float16*)alloc((size_t)512 * 256 * 2);
    _Float16* W2t = (_Float16*)alloc((size_t)256 * 64 * 2);
    int* cursor = counts;

    const int nb = (n + 255) / 256;     // 391 (< 512 for scan_b)
    const int rs = (n + 7) / 8;         // 12500 per XCD range

    transpose_w1<<<(512 * 256 + 255) / 256, 256, 0, stream>>>(W1, W1t);
    transpose_w2<<<(256 * 64 + 255) / 256, 256, 0, stream>>>(W2, W2t);

    mlp_kernel<<<n / 32, 256, 0, stream>>>(x, W1t, b1, W2t, b2, h0h, n);

    init_counts_kernel<<<nb, 256, 0, stream>>>(counts, n);
    count_kernel<<<1024, 256, 0, stream>>>(dstL, counts, e, rs, n);
    dinv_kernel<<<nb, 256, 0, stream>>>(counts, dinv, n);
    scan_a<<<nb, 256, 0, stream>>>(counts, rowptr, bsums, n);
    scan_b<<<1, 512, 0, stream>>>(bsums, boff, nb);
    scan_c<<<nb, 256, 0, stream>>>(rowptr, cursor, boff, n, e);
    fill_kernel<<<1024, 256, 0, stream>>>(srcL, dstL, cursor, srcs, e, rs, n);

    // ping-pong: h0h -> hp0 -> hp1 -> ... iter9 (odd) lands in hp1
    const int pgrid = (n * 64 + 255) / 256;
    const uint* hin = (const uint*)h0h;
    uint* bufs[2] = {(uint*)hp0, (uint*)hp1};
    for (int it = 0; it < 10; ++it) {
        uint* hn = bufs[it & 1];
        prop_kernel<<<pgrid, 256, 0, stream>>>(hin, (const uint*)h0h, hn,
                                               rowptr, srcs, dinv, n);
        hin = hn;
    }
    logsoftmax_kernel<<<pgrid, 256, 0, stream>>>((const _Float16*)hin, out, n);
}

// Round 8
// 1444.847 us; speedup vs baseline: 1.6922x; 1.0988x over previous
//
#include <hip/hip_runtime.h>
#include <cstdint>
#include <cstddef>

// APPNP: h0 = relu(x@W1+b1)@W2+b2 ; 10x { h = 0.9*A_hat h + 0.1*h0 } ; log_softmax
// N=100000, E=3200000, F=512, H=256, C=64
// R6 (2nd resubmit; R6/R7 benches were infra timeouts, no data): MLP staged-LDS
//     W1 with pre-TILED weights (W1tt[16][256][32], each k-tile contiguous ->
//     coalesced staging), double-buffered, 1 barrier/step, loads issued before
//     MFMA. Prop: dinv-fold (g = dinv*h) kills the per-edge dinv gather + mul;
//     A=0.9*di^2 precomputed. Preproc before MLP.
// ws ~53 MB (R1 failed ~104 MB).

typedef _Float16 half8 __attribute__((ext_vector_type(8)));
typedef float floatx4 __attribute__((ext_vector_type(4)));

__device__ inline float2 unpack2(uint u) {
    union { uint u; _Float16 h[2]; } c; c.u = u;
    return make_float2((float)c.h[0], (float)c.h[1]);
}
__device__ inline uint pack2(float a, float b) {
    union { uint u; _Float16 h[2]; } c; c.h[0] = (_Float16)a; c.h[1] = (_Float16)b;
    return c.u;
}

// ---- W1 [512][256] f32 -> tiled f16 W1tt[kt][c][j] = W1[(kt*32+j)][c] ----
__global__ void transpose_w1_tiled(const float* __restrict__ W1, _Float16* __restrict__ W1tt) {
    int i = blockIdx.x * 256 + threadIdx.x;     // over 131072, write-coalesced
    if (i < 512 * 256) {
        int kt = i >> 13, c = (i >> 5) & 255, j = i & 31;
        W1tt[i] = (_Float16)W1[(size_t)(kt * 32 + j) * 256 + c];
    }
}
__global__ void transpose_w2(const float* __restrict__ W2, _Float16* __restrict__ W2t) {
    int i = blockIdx.x * 256 + threadIdx.x;     // over 256*64
    if (i < 256 * 64) {
        int k = i >> 6, c = i & 63;
        W2t[(size_t)c * 256 + k] = (_Float16)W2[i];
    }
}

// ---------------- fused 2-layer MLP via f16 MFMA ----------------
// block = 256 thr = 4 waves; 32 rows/block (3125 blocks exactly).
// phase1: wave (wr=wid>>1, wc=wid&1): rows wr*16..+15, cols wc*128..+127.
// W1 k-tiles staged into dbuf LDS: tile kt contiguous 16KB in W1tt, padded to
// rows of 40 f16 in LDS (80B stride -> balanced bank quads).
// frag maps (16x16x32): A[row=l&15][k=(l>>4)*8+j]; B[k..][col=l&15];
//                       D[row=(l>>4)*4+r][col=l&15]   (m89-verified)
__global__ __launch_bounds__(256) void mlp_kernel(
    const float* __restrict__ x, const _Float16* __restrict__ W1tt,
    const float* __restrict__ b1, const _Float16* __restrict__ W2t,
    const float* __restrict__ b2, const float* __restrict__ dinv,
    _Float16* __restrict__ g0h, int n)
{
    __shared__ __align__(16) _Float16 xs[32][520];      // 33.3 KB
    __shared__ __align__(16) _Float16 wraw[2][10240];   // 40 KB dbuf [256][40]; reused as hmid

    const int tid  = threadIdx.x;
    const int lane = tid & 63;
    const int wid  = tid >> 6;
    const int r0blk = blockIdx.x * 32;
    const int lr = lane & 15;
    const int lg = lane >> 4;

    // ---- load x tile 32x512 fp32 -> f16 LDS ----
    for (int fi = tid; fi < 32 * 128; fi += 256) {
        int r = fi >> 7, k4 = (fi & 127) * 4;
        float4 v = *(const float4*)(x + (size_t)(r0blk + r) * 512 + k4);
        union { short4 s; _Float16 h[4]; } c;
        c.h[0] = (_Float16)v.x; c.h[1] = (_Float16)v.y;
        c.h[2] = (_Float16)v.z; c.h[3] = (_Float16)v.w;
        *(short4*)&xs[r][k4] = c.s;
    }

    const int wr = wid >> 1, wc = wid & 1;
    floatx4 acc1[8];
#pragma unroll
    for (int ct = 0; ct < 8; ++ct) {
        float b = b1[wc * 128 + ct * 16 + lr];
        acc1[ct] = (floatx4){b, b, b, b};
    }

    // staging helpers: tile kt = 8192 f16 contiguous; thread t owns chunks
    // t, t+256, t+512, t+768 (16B each); chunk ch -> col c=ch>>2, seg=ch&3.
    const int sc = tid >> 2, ss = (tid & 3) * 8;     // col, f16-offset within col
    int4 st0, st1, st2, st3;
    {
        const int4* gs = (const int4*)(W1tt);        // tile 0
        st0 = gs[tid]; st1 = gs[tid + 256]; st2 = gs[tid + 512]; st3 = gs[tid + 768];
    }
    {
        _Float16* wb = wraw[0];
        *(int4*)&wb[(sc +   0) * 40 + ss] = st0;
        *(int4*)&wb[(sc +  64) * 40 + ss] = st1;
        *(int4*)&wb[(sc + 128) * 40 + ss] = st2;
        *(int4*)&wb[(sc + 192) * 40 + ss] = st3;
    }
    __syncthreads();   // xs + buf0 visible

    for (int kt = 0; kt < 16; ++kt) {
        const int cur = kt & 1;
        if (kt < 15) {   // issue next-tile loads; latency hides under MFMA below
            const int4* gs = (const int4*)(W1tt + (size_t)(kt + 1) * 8192);
            st0 = gs[tid]; st1 = gs[tid + 256]; st2 = gs[tid + 512]; st3 = gs[tid + 768];
        }
        const _Float16* wb = wraw[cur];
        half8 a = *(const half8*)&xs[wr * 16 + lr][kt * 32 + lg * 8];
#pragma unroll
        for (int ct = 0; ct < 8; ++ct) {
            half8 b = *(const half8*)&wb[(wc * 128 + ct * 16 + lr) * 40 + lg * 8];
            acc1[ct] = __builtin_amdgcn_mfma_f32_16x16x32_f16(a, b, acc1[ct], 0, 0, 0);
        }
        if (kt < 15) {
            _Float16* wn = wraw[cur ^ 1];
            *(int4*)&wn[(sc +   0) * 40 + ss] = st0;
            *(int4*)&wn[(sc +  64) * 40 + ss] = st1;
            *(int4*)&wn[(sc + 128) * 40 + ss] = st2;
            *(int4*)&wn[(sc + 192) * 40 + ss] = st3;
        }
        __syncthreads();
    }

    // ---- hmid = relu(...), store f16 into wraw[0] region as [32][264] ----
    _Float16 (*hmid)[264] = (_Float16(*)[264])&wraw[0][0];
#pragma unroll
    for (int ct = 0; ct < 8; ++ct) {
#pragma unroll
        for (int r = 0; r < 4; ++r) {
            float v = fmaxf(acc1[ct][r], 0.f);
            hmid[wr * 16 + lg * 4 + r][wc * 128 + ct * 16 + lr] = (_Float16)v;
        }
    }
    __syncthreads();

    // ---- phase 2: g0 = dinv * (hmid @ W2 + b2), 32 x 64 ----
    const int rt = wid >> 1, ct2 = (wid & 1) * 2;
    floatx4 acc2[2] = {(floatx4){0,0,0,0}, (floatx4){0,0,0,0}};
#pragma unroll 2
    for (int kk = 0; kk < 256; kk += 32) {
        half8 a = *(const half8*)&hmid[rt * 16 + lr][kk + lg * 8];
#pragma unroll
        for (int q = 0; q < 2; ++q) {
            half8 b = *(const half8*)&W2t[(size_t)((ct2 + q) * 16 + lr) * 256 + kk + lg * 8];
            acc2[q] = __builtin_amdgcn_mfma_f32_16x16x32_f16(a, b, acc2[q], 0, 0, 0);
        }
    }
#pragma unroll
    for (int q = 0; q < 2; ++q) {
        int col = (ct2 + q) * 16 + lr;
        float bb = b2[col];
#pragma unroll
        for (int r = 0; r < 4; ++r) {
            int row = r0blk + rt * 16 + lg * 4 + r;
            float di = dinv[row];
            g0h[(size_t)row * 64 + col] = (_Float16)(di * (acc2[q][r] + bb));
        }
    }
}

// ---------------- graph preprocessing (CSR by dst, XCD-range partitioned) ----------------
__global__ void init_counts_kernel(int* __restrict__ counts, int n) {
    int i = blockIdx.x * blockDim.x + threadIdx.x;
    if (i < n) counts[i] = 1;   // self-loop
}

__global__ void count_kernel(const int* __restrict__ dstL, int* __restrict__ counts,
                             int e, int rs, int n) {
    const int r = blockIdx.x & 7;
    const int g = blockIdx.x >> 3;
    const int B = gridDim.x >> 3;
    const int lo = r * rs;
    const int hi = min(lo + rs, n);
    for (int i = g * blockDim.x + threadIdx.x; i < e; i += B * blockDim.x) {
        int d = dstL[i];
        if (d >= lo && d < hi) atomicAdd(&counts[d], 1);
    }
}

// dinv = deg^-1/2 ; A = 0.9 * dinv^2 = 0.9/deg
__global__ void dinv_kernel(const int* __restrict__ counts, float* __restrict__ dinv,
                            float* __restrict__ Anode, int n) {
    int i = blockIdx.x * blockDim.x + threadIdx.x;
    if (i < n) {
        float deg = (float)counts[i];              // >= 1 (self-loop)
        dinv[i] = 1.0f / sqrtf(deg);
        Anode[i] = 0.9f / deg;
    }
}

__global__ __launch_bounds__(256) void scan_a(const int* __restrict__ counts,
                                              int* __restrict__ rowptr,
                                              int* __restrict__ bsums, int n)
{
    __shared__ int s[256];
    const int t = threadIdx.x;
    const int i = blockIdx.x * 256 + t;
    int v = (i < n) ? (counts[i] - 1) : 0;
    s[t] = v;
    __syncthreads();
    for (int off = 1; off < 256; off <<= 1) {
        int add = (t >= off) ? s[t - off] : 0;
        __syncthreads();
        s[t] += add;
        __syncthreads();
    }
    if (i < n) rowptr[i] = s[t] - v;
    if (t == 255) bsums[blockIdx.x] = s[255];
}

__global__ __launch_bounds__(512) void scan_b(const int* __restrict__ bsums,
                                              int* __restrict__ boff, int nb)
{
    __shared__ int s[512];
    const int t = threadIdx.x;
    int v = (t < nb) ? bsums[t] : 0;
    s[t] = v;
    __syncthreads();
    for (int off = 1; off < 512; off <<= 1) {
        int add = (t >= off) ? s[t - off] : 0;
        __syncthreads();
        s[t] += add;
        __syncthreads();
    }
    if (t < nb) boff[t] = s[t] - v;
}

__global__ __launch_bounds__(256) void scan_c(int* __restrict__ rowptr,
                                              int* __restrict__ cursor,
                                              const int* __restrict__ boff, int n, int e)
{
    int i = blockIdx.x * 256 + threadIdx.x;
    if (i < n) {
        int v = rowptr[i] + boff[blockIdx.x];
        rowptr[i] = v;
        cursor[i] = v;
    }
    if (i == 0) rowptr[n] = e;
}

__global__ void fill_kernel(const int* __restrict__ srcL, const int* __restrict__ dstL,
                            int* __restrict__ cursor, int* __restrict__ srcs,
                            int e, int rs, int n) {
    const int r = blockIdx.x & 7;
    const int g = blockIdx.x >> 3;
    const int B = gridDim.x >> 3;
    const int lo = r * rs;
    const int hi = min(lo + rs, n);
    for (int i = g * blockDim.x + threadIdx.x; i < e; i += B * blockDim.x) {
        int d = dstL[i];
        if (d >= lo && d < hi) {
            int pos = atomicAdd(&cursor[d], 1);
            srcs[pos] = srcL[i];
        }
    }
}

// ---------------- APPNP propagation step on g = dinv .* h ----------------
// g_new[i] = A[i]*(sum_src g[src] + g[i]) + 0.1*g0[i],  A = 0.9*dinv^2
// wave per node; half = lane>>5 takes alternate edges; p = lane&31 = feat-pair.
__global__ __launch_bounds__(256) void prop_kernel(
    const uint* __restrict__ gu, const uint* __restrict__ g0u,
    uint* __restrict__ gnu, const int* __restrict__ rowptr,
    const int* __restrict__ srcs, const float* __restrict__ Anode, int n)
{
    const int node = (blockIdx.x * blockDim.x + threadIdx.x) >> 6;
    if (node >= n) return;
    const int lane = threadIdx.x & 63;
    const int half_ = lane >> 5;
    const int p = lane & 31;
    const int e0 = rowptr[node], e1 = rowptr[node + 1];
    float accx = 0.f, accy = 0.f;
    int e = e0 + half_;
    for (; e + 6 < e1; e += 8) {
        int s0 = srcs[e], s1 = srcs[e + 2], s2 = srcs[e + 4], s3 = srcs[e + 6];
        float2 f0 = unpack2(gu[(size_t)s0 * 32 + p]);
        float2 f1 = unpack2(gu[(size_t)s1 * 32 + p]);
        float2 f2 = unpack2(gu[(size_t)s2 * 32 + p]);
        float2 f3 = unpack2(gu[(size_t)s3 * 32 + p]);
        accx += f0.x; accy += f0.y;
        accx += f1.x; accy += f1.y;
        accx += f2.x; accy += f2.y;
        accx += f3.x; accy += f3.y;
    }
    for (; e < e1; e += 2) {
        float2 f = unpack2(gu[(size_t)srcs[e] * 32 + p]);
        accx += f.x; accy += f.y;
    }
    accx += __shfl_xor(accx, 32);
    accy += __shfl_xor(accy, 32);

    const float A = Anode[node];
    float2 self = unpack2(gu[(size_t)node * 32 + p]);
    float2 anc  = unpack2(g0u[(size_t)node * 32 + p]);
    float ox = A * (accx + self.x) + 0.1f * anc.x;
    float oy = A * (accy + self.y) + 0.1f * anc.y;
    if (half_ == 0) gnu[(size_t)node * 32 + p] = pack2(ox, oy);
}

// ---------------- log_softmax over C=64 (g/dinv, fp32 out) ----------------
__global__ __launch_bounds__(256) void logsoftmax_kernel(
    const _Float16* __restrict__ g, const float* __restrict__ dinv,
    float* __restrict__ out, int n)
{
    const int row = (blockIdx.x * blockDim.x + threadIdx.x) >> 6;
    const int lane = threadIdx.x & 63;
    if (row >= n) return;
    float v = (float)g[(size_t)row * 64 + lane] / dinv[row];
    float m = v;
#pragma unroll
    for (int o = 32; o > 0; o >>= 1) m = fmaxf(m, __shfl_xor(m, o));
    float ex = expf(v - m);
    float s = ex;
#pragma unroll
    for (int o = 32; o > 0; o >>= 1) s += __shfl_xor(s, o);
    out[(size_t)row * 64 + lane] = v - m - logf(s);
}

// ---------------- launcher ----------------
extern "C" void kernel_launch(void* const* d_in, const int* in_sizes, int n_in,
                              void* d_out, int out_size, void* d_ws, size_t ws_size,
                              hipStream_t stream)
{
    const float* x  = (const float*)d_in[0];
    const int*   ei = (const int*)d_in[1];
    const float* W1 = (const float*)d_in[2];
    const float* b1 = (const float*)d_in[3];
    const float* W2 = (const float*)d_in[4];
    const float* b2 = (const float*)d_in[5];
    float* out = (float*)d_out;

    const int n = in_sizes[0] / 512;    // 100000
    const int e = in_sizes[1] / 2;      // 3200000
    const int* srcL = ei;
    const int* dstL = ei + e;

    char* wsb = (char*)d_ws;
    size_t off = 0;
    auto alloc = [&](size_t bytes) -> void* {
        void* p = wsb + off;
        off = (off + bytes + 255) & ~(size_t)255;
        return p;
    };
    // ~53 MB total
    _Float16* g0h = (_Float16*)alloc((size_t)n * 64 * 2);  // 12.8 MB
    _Float16* gp0 = (_Float16*)alloc((size_t)n * 64 * 2);  // 12.8 MB
    _Float16* gp1 = (_Float16*)alloc((size_t)n * 64 * 2);  // 12.8 MB
    int*   srcs   = (int*)alloc((size_t)e * 4);            // 12.8 MB
    float* dinv   = (float*)alloc((size_t)n * 4);
    float* Anode  = (float*)alloc((size_t)n * 4);
    int*   counts = (int*)alloc((size_t)n * 4);            // reused as cursor
    int*   rowptr = (int*)alloc((size_t)(n + 1) * 4);
    int*   bsums  = (int*)alloc(4096);
    int*   boff   = (int*)alloc(4096);
    _Float16* W1tt = (_Float16*)alloc((size_t)512 * 256 * 2);
    _Float16* W2t  = (_Float16*)alloc((size_t)256 * 64 * 2);
    int* cursor = counts;

    const int nb = (n + 255) / 256;     // 391 (< 512 for scan_b)
    const int rs = (n + 7) / 8;         // 12500 per XCD range

    transpose_w1_tiled<<<(512 * 256 + 255) / 256, 256, 0, stream>>>(W1, W1tt);
    transpose_w2<<<(256 * 64 + 255) / 256, 256, 0, stream>>>(W2, W2t);

    // preprocessing first: mlp epilogue needs dinv
    init_counts_kernel<<<nb, 256, 0, stream>>>(counts, n);
    count_kernel<<<1024, 256, 0, stream>>>(dstL, counts, e, rs, n);
    dinv_kernel<<<nb, 256, 0, stream>>>(counts, dinv, Anode, n);
    scan_a<<<nb, 256, 0, stream>>>(counts, rowptr, bsums, n);
    scan_b<<<1, 512, 0, stream>>>(bsums, boff, nb);
    scan_c<<<nb, 256, 0, stream>>>(rowptr, cursor, boff, n, e);
    fill_kernel<<<1024, 256, 0, stream>>>(srcL, dstL, cursor, srcs, e, rs, n);

    mlp_kernel<<<n / 32, 256, 0, stream>>>(x, W1tt, b1, W2t, b2, dinv, g0h, n);

    // ping-pong: g0h -> gp0 -> gp1 -> ... iter9 (odd) lands in gp1
    const int pgrid = (n * 64 + 255) / 256;
    const uint* gin = (const uint*)g0h;
    uint* bufs[2] = {(uint*)gp0, (uint*)gp1};
    for (int it = 0; it < 10; ++it) {
        uint* gn = bufs[it & 1];
        prop_kernel<<<pgrid, 256, 0, stream>>>(gin, (const uint*)g0h, gn,
                                               rowptr, srcs, Anode, n);
        gin = gn;
    }
    logsoftmax_kernel<<<pgrid, 256, 0, stream>>>((const _Float16*)gin, dinv, out, n);
}

// Round 9
// 1435.430 us; speedup vs baseline: 1.7033x; 1.0066x over previous
//
#include <hip/hip_runtime.h>
#include <cstdint>
#include <cstddef>

// APPNP: h0 = relu(x@W1+b1)@W2+b2 ; 10x { h = 0.9*A_hat h + 0.1*h0 } ; log_softmax
// N=100000, E=3200000, F=512, H=256, C=64
// R9: MLP without ANY weight LDS staging: fragment-contiguous weight layout
//     W1tc[kt][ctile][col][k32] -> one B-frag read = 1KB contiguous from L2
//     (R5's failure was the 1KB-STRIDED scatter; R8's staging cost 74KB LDS ->
//     2 blocks/CU + 1.4e7 bank conflicts). 2 barriers total, 50KB LDS ->
//     3 blocks/CU. Waves partition columns (W read once per block).
//     Prop: 8-deep gather pipeline per half-wave.
// ws ~53 MB (R1 failed ~104 MB).

typedef _Float16 half8 __attribute__((ext_vector_type(8)));
typedef float floatx4 __attribute__((ext_vector_type(4)));

__device__ inline float2 unpack2(uint u) {
    union { uint u; _Float16 h[2]; } c; c.u = u;
    return make_float2((float)c.h[0], (float)c.h[1]);
}
__device__ inline uint pack2(float a, float b) {
    union { uint u; _Float16 h[2]; } c; c.h[0] = (_Float16)a; c.h[1] = (_Float16)b;
    return c.u;
}

// ---- W1 [512][256] f32 -> frag-contiguous f16:
//      W1tc[((kt*16 + ctile)*16 + col)*32 + j] = W1[(kt*32+j)*256 + ctile*16+col]
__global__ void transpose_w1c(const float* __restrict__ W1, _Float16* __restrict__ W1tc) {
    int i = blockIdx.x * 256 + threadIdx.x;      // over 131072, write-coalesced
    if (i < 512 * 256) {
        int kt = i >> 13, ctile = (i >> 9) & 15, col = (i >> 5) & 15, j = i & 31;
        W1tc[i] = (_Float16)W1[(size_t)(kt * 32 + j) * 256 + ctile * 16 + col];
    }
}
// ---- W2 [256][64] f32 -> W2tc[((kt*4 + ct)*16 + col)*32 + j] ----
__global__ void transpose_w2c(const float* __restrict__ W2, _Float16* __restrict__ W2tc) {
    int i = blockIdx.x * 256 + threadIdx.x;      // over 16384
    if (i < 256 * 64) {
        int kt = i >> 11, ct = (i >> 9) & 3, col = (i >> 5) & 15, j = i & 31;
        W2tc[i] = (_Float16)W2[(size_t)(kt * 32 + j) * 64 + ct * 16 + col];
    }
}

// ---------------- fused 2-layer MLP via f16 MFMA, frag-coalesced L2 weights ----------------
// block = 256 thr = 4 waves; 32 rows/block (3125 blocks).
// phase1: wave w owns cols w*64..+63 (ctiles w*4..+3), ALL 32 rows -> W1 read
//         once per block. B-frag = 1KB contiguous global read (8 lines, L2-hit).
// frag maps (16x16x32): A[row=l&15][k=(l>>4)*8+j]; B[k=(l>>4)*8+j][col=l&15];
//                       D[row=(l>>4)*4+r][col=l&15]   (m89-verified)
__global__ __launch_bounds__(256) void mlp_kernel(
    const float* __restrict__ x, const _Float16* __restrict__ W1tc,
    const float* __restrict__ b1, const _Float16* __restrict__ W2tc,
    const float* __restrict__ b2, const float* __restrict__ dinv,
    _Float16* __restrict__ g0h, int n)
{
    __shared__ __align__(16) _Float16 xs[32][520];     // 33.3 KB
    __shared__ __align__(16) _Float16 hmid[32][264];   // 16.9 KB (total 50.2 KB)

    const int tid  = threadIdx.x;
    const int lane = tid & 63;
    const int wid  = tid >> 6;
    const int r0blk = blockIdx.x * 32;
    const int lr = lane & 15;
    const int lg = lane >> 4;

    // ---- load x tile 32x512 fp32 -> f16 LDS (coalesced float4) ----
    for (int fi = tid; fi < 32 * 128; fi += 256) {
        int r = fi >> 7, k4 = (fi & 127) * 4;
        float4 v = *(const float4*)(x + (size_t)(r0blk + r) * 512 + k4);
        union { short4 s; _Float16 h[4]; } c;
        c.h[0] = (_Float16)v.x; c.h[1] = (_Float16)v.y;
        c.h[2] = (_Float16)v.z; c.h[3] = (_Float16)v.w;
        *(short4*)&xs[r][k4] = c.s;
    }
    __syncthreads();

    // ---- phase 1: hmid = relu(x @ W1 + b1); wave wid: cols wid*64..+63 ----
    floatx4 acc1[2][4];
#pragma unroll
    for (int c = 0; c < 4; ++c) {
        float b = b1[wid * 64 + c * 16 + lr];
        acc1[0][c] = (floatx4){b, b, b, b};
        acc1[1][c] = (floatx4){b, b, b, b};
    }

#pragma unroll 2
    for (int kt = 0; kt < 16; ++kt) {
        half8 bf[4];
#pragma unroll
        for (int c = 0; c < 4; ++c)
            bf[c] = *(const half8*)&W1tc[(((size_t)kt * 16 + wid * 4 + c) * 16 + lr) * 32 + lg * 8];
        half8 a0 = *(const half8*)&xs[lr][kt * 32 + lg * 8];
        half8 a1 = *(const half8*)&xs[16 + lr][kt * 32 + lg * 8];
#pragma unroll
        for (int c = 0; c < 4; ++c) {
            acc1[0][c] = __builtin_amdgcn_mfma_f32_16x16x32_f16(a0, bf[c], acc1[0][c], 0, 0, 0);
            acc1[1][c] = __builtin_amdgcn_mfma_f32_16x16x32_f16(a1, bf[c], acc1[1][c], 0, 0, 0);
        }
    }

#pragma unroll
    for (int rt = 0; rt < 2; ++rt)
#pragma unroll
        for (int c = 0; c < 4; ++c)
#pragma unroll
            for (int r = 0; r < 4; ++r) {
                float v = fmaxf(acc1[rt][c][r], 0.f);
                hmid[rt * 16 + lg * 4 + r][wid * 64 + c * 16 + lr] = (_Float16)v;
            }
    __syncthreads();

    // ---- phase 2: g0 = dinv * (hmid @ W2 + b2), 32 x 64 ----
    const int rt = wid >> 1, ct2 = (wid & 1) * 2;
    floatx4 acc2[2] = {(floatx4){0,0,0,0}, (floatx4){0,0,0,0}};
#pragma unroll
    for (int kt = 0; kt < 8; ++kt) {
        half8 a = *(const half8*)&hmid[rt * 16 + lr][kt * 32 + lg * 8];
#pragma unroll
        for (int q = 0; q < 2; ++q) {
            half8 b = *(const half8*)&W2tc[((size_t)(kt * 4 + ct2 + q) * 16 + lr) * 32 + lg * 8];
            acc2[q] = __builtin_amdgcn_mfma_f32_16x16x32_f16(a, b, acc2[q], 0, 0, 0);
        }
    }
#pragma unroll
    for (int q = 0; q < 2; ++q) {
        int col = (ct2 + q) * 16 + lr;
        float bb = b2[col];
#pragma unroll
        for (int r = 0; r < 4; ++r) {
            int row = r0blk + rt * 16 + lg * 4 + r;
            float di = dinv[row];
            g0h[(size_t)row * 64 + col] = (_Float16)(di * (acc2[q][r] + bb));
        }
    }
}

// ---------------- graph preprocessing (CSR by dst, XCD-range partitioned) ----------------
__global__ void init_counts_kernel(int* __restrict__ counts, int n) {
    int i = blockIdx.x * blockDim.x + threadIdx.x;
    if (i < n) counts[i] = 1;   // self-loop
}

__global__ void count_kernel(const int* __restrict__ dstL, int* __restrict__ counts,
                             int e, int rs, int n) {
    const int r = blockIdx.x & 7;
    const int g = blockIdx.x >> 3;
    const int B = gridDim.x >> 3;
    const int lo = r * rs;
    const int hi = min(lo + rs, n);
    for (int i = g * blockDim.x + threadIdx.x; i < e; i += B * blockDim.x) {
        int d = dstL[i];
        if (d >= lo && d < hi) atomicAdd(&counts[d], 1);
    }
}

// dinv = deg^-1/2 ; A = 0.9 * dinv^2 = 0.9/deg
__global__ void dinv_kernel(const int* __restrict__ counts, float* __restrict__ dinv,
                            float* __restrict__ Anode, int n) {
    int i = blockIdx.x * blockDim.x + threadIdx.x;
    if (i < n) {
        float deg = (float)counts[i];              // >= 1 (self-loop)
        dinv[i] = 1.0f / sqrtf(deg);
        Anode[i] = 0.9f / deg;
    }
}

__global__ __launch_bounds__(256) void scan_a(const int* __restrict__ counts,
                                              int* __restrict__ rowptr,
                                              int* __restrict__ bsums, int n)
{
    __shared__ int s[256];
    const int t = threadIdx.x;
    const int i = blockIdx.x * 256 + t;
    int v = (i < n) ? (counts[i] - 1) : 0;
    s[t] = v;
    __syncthreads();
    for (int off = 1; off < 256; off <<= 1) {
        int add = (t >= off) ? s[t - off] : 0;
        __syncthreads();
        s[t] += add;
        __syncthreads();
    }
    if (i < n) rowptr[i] = s[t] - v;
    if (t == 255) bsums[blockIdx.x] = s[255];
}

__global__ __launch_bounds__(512) void scan_b(const int* __restrict__ bsums,
                                              int* __restrict__ boff, int nb)
{
    __shared__ int s[512];
    const int t = threadIdx.x;
    int v = (t < nb) ? bsums[t] : 0;
    s[t] = v;
    __syncthreads();
    for (int off = 1; off < 512; off <<= 1) {
        int add = (t >= off) ? s[t - off] : 0;
        __syncthreads();
        s[t] += add;
        __syncthreads();
    }
    if (t < nb) boff[t] = s[t] - v;
}

__global__ __launch_bounds__(256) void scan_c(int* __restrict__ rowptr,
                                              int* __restrict__ cursor,
                                              const int* __restrict__ boff, int n, int e)
{
    int i = blockIdx.x * 256 + threadIdx.x;
    if (i < n) {
        int v = rowptr[i] + boff[blockIdx.x];
        rowptr[i] = v;
        cursor[i] = v;
    }
    if (i == 0) rowptr[n] = e;
}

__global__ void fill_kernel(const int* __restrict__ srcL, const int* __restrict__ dstL,
                            int* __restrict__ cursor, int* __restrict__ srcs,
                            int e, int rs, int n) {
    const int r = blockIdx.x & 7;
    const int g = blockIdx.x >> 3;
    const int B = gridDim.x >> 3;
    const int lo = r * rs;
    const int hi = min(lo + rs, n);
    for (int i = g * blockDim.x + threadIdx.x; i < e; i += B * blockDim.x) {
        int d = dstL[i];
        if (d >= lo && d < hi) {
            int pos = atomicAdd(&cursor[d], 1);
            srcs[pos] = srcL[i];
        }
    }
}

// ---------------- APPNP propagation step on g = dinv .* h ----------------
// g_new[i] = A[i]*(sum_src g[src] + g[i]) + 0.1*g0[i],  A = 0.9*dinv^2
// wave per node; half = lane>>5 takes alternate edges; p = lane&31 = feat-pair.
// 8 gathers in flight per half (16/wave) to cover L3 latency.
__global__ __launch_bounds__(256) void prop_kernel(
    const uint* __restrict__ gu, const uint* __restrict__ g0u,
    uint* __restrict__ gnu, const int* __restrict__ rowptr,
    const int* __restrict__ srcs, const float* __restrict__ Anode, int n)
{
    const int node = (blockIdx.x * blockDim.x + threadIdx.x) >> 6;
    if (node >= n) return;
    const int lane = threadIdx.x & 63;
    const int half_ = lane >> 5;
    const int p = lane & 31;
    const int e0 = rowptr[node], e1 = rowptr[node + 1];
    float accx = 0.f, accy = 0.f;
    int e = e0 + half_;
    for (; e + 14 < e1; e += 16) {
        int s0 = srcs[e],      s1 = srcs[e + 2],  s2 = srcs[e + 4],  s3 = srcs[e + 6];
        int s4 = srcs[e + 8],  s5 = srcs[e + 10], s6 = srcs[e + 12], s7 = srcs[e + 14];
        float2 f0 = unpack2(gu[(size_t)s0 * 32 + p]);
        float2 f1 = unpack2(gu[(size_t)s1 * 32 + p]);
        float2 f2 = unpack2(gu[(size_t)s2 * 32 + p]);
        float2 f3 = unpack2(gu[(size_t)s3 * 32 + p]);
        float2 f4 = unpack2(gu[(size_t)s4 * 32 + p]);
        float2 f5 = unpack2(gu[(size_t)s5 * 32 + p]);
        float2 f6 = unpack2(gu[(size_t)s6 * 32 + p]);
        float2 f7 = unpack2(gu[(size_t)s7 * 32 + p]);
        accx += f0.x; accy += f0.y;
        accx += f1.x; accy += f1.y;
        accx += f2.x; accy += f2.y;
        accx += f3.x; accy += f3.y;
        accx += f4.x; accy += f4.y;
        accx += f5.x; accy += f5.y;
        accx += f6.x; accy += f6.y;
        accx += f7.x; accy += f7.y;
    }
    for (; e < e1; e += 2) {
        float2 f = unpack2(gu[(size_t)srcs[e] * 32 + p]);
        accx += f.x; accy += f.y;
    }
    accx += __shfl_xor(accx, 32);
    accy += __shfl_xor(accy, 32);

    const float A = Anode[node];
    float2 self = unpack2(gu[(size_t)node * 32 + p]);
    float2 anc  = unpack2(g0u[(size_t)node * 32 + p]);
    float ox = A * (accx + self.x) + 0.1f * anc.x;
    float oy = A * (accy + self.y) + 0.1f * anc.y;
    if (half_ == 0) gnu[(size_t)node * 32 + p] = pack2(ox, oy);
}

// ---------------- log_softmax over C=64 (g/dinv, fp32 out) ----------------
__global__ __launch_bounds__(256) void logsoftmax_kernel(
    const _Float16* __restrict__ g, const float* __restrict__ dinv,
    float* __restrict__ out, int n)
{
    const int row = (blockIdx.x * blockDim.x + threadIdx.x) >> 6;
    const int lane = threadIdx.x & 63;
    if (row >= n) return;
    float v = (float)g[(size_t)row * 64 + lane] / dinv[row];
    float m = v;
#pragma unroll
    for (int o = 32; o > 0; o >>= 1) m = fmaxf(m, __shfl_xor(m, o));
    float ex = expf(v - m);
    float s = ex;
#pragma unroll
    for (int o = 32; o > 0; o >>= 1) s += __shfl_xor(s, o);
    out[(size_t)row * 64 + lane] = v - m - logf(s);
}

// ---------------- launcher ----------------
extern "C" void kernel_launch(void* const* d_in, const int* in_sizes, int n_in,
                              void* d_out, int out_size, void* d_ws, size_t ws_size,
                              hipStream_t stream)
{
    const float* x  = (const float*)d_in[0];
    const int*   ei = (const int*)d_in[1];
    const float* W1 = (const float*)d_in[2];
    const float* b1 = (const float*)d_in[3];
    const float* W2 = (const float*)d_in[4];
    const float* b2 = (const float*)d_in[5];
    float* out = (float*)d_out;

    const int n = in_sizes[0] / 512;    // 100000
    const int e = in_sizes[1] / 2;      // 3200000
    const int* srcL = ei;
    const int* dstL = ei + e;

    char* wsb = (char*)d_ws;
    size_t off = 0;
    auto alloc = [&](size_t bytes) -> void* {
        void* p = wsb + off;
        off = (off + bytes + 255) & ~(size_t)255;
        return p;
    };
    // ~53 MB total
    _Float16* g0h = (_Float16*)alloc((size_t)n * 64 * 2);  // 12.8 MB
    _Float16* gp0 = (_Float16*)alloc((size_t)n * 64 * 2);  // 12.8 MB
    _Float16* gp1 = (_Float16*)alloc((size_t)n * 64 * 2);  // 12.8 MB
    int*   srcs   = (int*)alloc((size_t)e * 4);            // 12.8 MB
    float* dinv   = (float*)alloc((size_t)n * 4);
    float* Anode  = (float*)alloc((size_t)n * 4);
    int*   counts = (int*)alloc((size_t)n * 4);            // reused as cursor
    int*   rowptr = (int*)alloc((size_t)(n + 1) * 4);
    int*   bsums  = (int*)alloc(4096);
    int*   boff   = (int*)alloc(4096);
    _Float16* W1tc = (_Float16*)alloc((size_t)512 * 256 * 2);
    _Float16* W2tc = (_Float16*)alloc((size_t)256 * 64 * 2);
    int* cursor = counts;

    const int nb = (n + 255) / 256;     // 391 (< 512 for scan_b)
    const int rs = (n + 7) / 8;         // 12500 per XCD range

    transpose_w1c<<<(512 * 256 + 255) / 256, 256, 0, stream>>>(W1, W1tc);
    transpose_w2c<<<(256 * 64 + 255) / 256, 256, 0, stream>>>(W2, W2tc);

    // preprocessing first: mlp epilogue needs dinv
    init_counts_kernel<<<nb, 256, 0, stream>>>(counts, n);
    count_kernel<<<1024, 256, 0, stream>>>(dstL, counts, e, rs, n);
    dinv_kernel<<<nb, 256, 0, stream>>>(counts, dinv, Anode, n);
    scan_a<<<nb, 256, 0, stream>>>(counts, rowptr, bsums, n);
    scan_b<<<1, 512, 0, stream>>>(bsums, boff, nb);
    scan_c<<<nb, 256, 0, stream>>>(rowptr, cursor, boff, n, e);
    fill_kernel<<<1024, 256, 0, stream>>>(srcL, dstL, cursor, srcs, e, rs, n);

    mlp_kernel<<<n / 32, 256, 0, stream>>>(x, W1tc, b1, W2tc, b2, dinv, g0h, n);

    // ping-pong: g0h -> gp0 -> gp1 -> ... iter9 (odd) lands in gp1
    const int pgrid = (n * 64 + 255) / 256;
    const uint* gin = (const uint*)g0h;
    uint* bufs[2] = {(uint*)gp0, (uint*)gp1};
    for (int it = 0; it < 10; ++it) {
        uint* gn = bufs[it & 1];
        prop_kernel<<<pgrid, 256, 0, stream>>>(gin, (const uint*)g0h, gn,
                                               rowptr, srcs, Anode, n);
        gin = gn;
    }
    logsoftmax_kernel<<<pgrid, 256, 0, stream>>>((const _Float16*)gin, dinv, out, n);
}